// Round 1
// baseline (369.901 us; speedup 1.0000x reference)
//
#include <hip/hip_runtime.h>
#include <hip/hip_bf16.h>
#include <stdint.h>

#define HD 64
#define NH 16
#define TT 2048
#define DD 1024

typedef uint16_t u16;
typedef __bf16 bf16_t;
typedef bf16_t bf16x8 __attribute__((ext_vector_type(8)));
typedef float f32x4 __attribute__((ext_vector_type(4)));

__device__ __forceinline__ u16 f2b(float f) {
    union { float f; uint32_t u; } v; v.f = f;
    uint32_t u = v.u;
    u += 0x7fff + ((u >> 16) & 1);   // RNE
    return (u16)(u >> 16);
}

__device__ __forceinline__ void gload16(const void* g, void* l) {
    __builtin_amdgcn_global_load_lds(
        (__attribute__((address_space(1))) void*)g,
        (__attribute__((address_space(3))) void*)l, 16, 0, 0);
}

// ---------------- converts ----------------

__global__ void f32_to_bf16_vec(const float* __restrict__ in, u16* __restrict__ out, int n4) {
    int i = blockIdx.x * 256 + threadIdx.x;
    if (i >= n4) return;
    float4 v = ((const float4*)in)[i];
    ushort4 r;
    r.x = f2b(v.x); r.y = f2b(v.y); r.z = f2b(v.z); r.w = f2b(v.w);
    ((ushort4*)out)[i] = r;
}

// out[c][r] = bf16(in[r][c]); R,C multiples of 32; block (32,8)
__global__ void transpose_f32_bf16(const float* __restrict__ in, u16* __restrict__ out, int R, int C) {
    __shared__ float tile[32][33];
    const int tx = threadIdx.x, ty = threadIdx.y;
    const int c0 = blockIdx.x * 32, r0 = blockIdx.y * 32;
#pragma unroll
    for (int j = 0; j < 32; j += 8)
        tile[ty + j][tx] = in[(size_t)(r0 + ty + j) * C + c0 + tx];
    __syncthreads();
#pragma unroll
    for (int j = 0; j < 32; j += 8)
        out[(size_t)(c0 + ty + j) * R + r0 + tx] = f2b(tile[tx][ty + j]);
}

// ---------------- GEMM C = A[M,K] * Bt[N,K]^T, bf16 in, f32 acc ----------------
// MODE 0: scatter epilogue -> q (x0.125), k, vT   (N=3072)
// MODE 1: plain f32 store to of[M,N]

template<int MODE>
__global__ __launch_bounds__(256, 2)
void gemm_bt(const u16* __restrict__ A, const u16* __restrict__ Bt,
             int M, int N, int K,
             u16* __restrict__ oq, u16* __restrict__ ok, u16* __restrict__ ovT,
             float* __restrict__ of)
{
    __shared__ __align__(16) u16 As[128 * 32];
    __shared__ __align__(16) u16 Bs[128 * 32];
    const int tid = threadIdx.x;
    const int lane = tid & 63, l15 = lane & 15, g = lane >> 4;
    const int wv = tid >> 6, wr = wv >> 1, wc = wv & 1;
    const long row0 = (long)blockIdx.y * 128;
    const long col0 = (long)blockIdx.x * 128;

    const int cA = tid, cB = tid + 256;
    const u16* a0 = A + (row0 + (cA >> 2)) * K + (cA & 3) * 8;
    const u16* a1 = A + (row0 + (cB >> 2)) * K + (cB & 3) * 8;
    const u16* b0 = Bt + (col0 + (cA >> 2)) * K + (cA & 3) * 8;
    const u16* b1 = Bt + (col0 + (cB >> 2)) * K + (cB & 3) * 8;

    const f32x4 z4 = {0.f, 0.f, 0.f, 0.f};
    f32x4 acc[4][4];
#pragma unroll
    for (int i = 0; i < 4; i++)
#pragma unroll
        for (int n = 0; n < 4; n++) acc[i][n] = z4;

    for (int k0 = 0; k0 < K; k0 += 32) {
        gload16(a0 + k0, &As[cA * 8]);
        gload16(a1 + k0, &As[cB * 8]);
        gload16(b0 + k0, &Bs[cA * 8]);
        gload16(b1 + k0, &Bs[cB * 8]);
        __syncthreads();
        bf16x8 af[4], bfr[4];
#pragma unroll
        for (int i = 0; i < 4; i++) af[i]  = *(const bf16x8*)&As[(wr * 64 + i * 16 + l15) * 32 + g * 8];
#pragma unroll
        for (int n = 0; n < 4; n++) bfr[n] = *(const bf16x8*)&Bs[(wc * 64 + n * 16 + l15) * 32 + g * 8];
#pragma unroll
        for (int i = 0; i < 4; i++)
#pragma unroll
            for (int n = 0; n < 4; n++)
                acc[i][n] = __builtin_amdgcn_mfma_f32_16x16x32_bf16(af[i], bfr[n], acc[i][n], 0, 0, 0);
        __syncthreads();
    }

    if (MODE == 0) {
        const int which = (int)(col0 >> 10);
        const long b = row0 >> 11;
#pragma unroll
        for (int i = 0; i < 4; i++) {
            const long r = row0 + wr * 64 + i * 16 + g * 4;
            const long t = r & (TT - 1);
#pragma unroll
            for (int n = 0; n < 4; n++) {
                const long c = col0 + wc * 64 + n * 16 + l15;
                const int h  = (int)((c >> 6) & 15);
                const int hd = (int)(c & 63);
                if (which == 0) {
#pragma unroll
                    for (int e = 0; e < 4; e++)
                        oq[((b * NH + h) * TT + t + e) * HD + hd] = f2b(acc[i][n][e] * 0.125f);
                } else if (which == 1) {
#pragma unroll
                    for (int e = 0; e < 4; e++)
                        ok[((b * NH + h) * TT + t + e) * HD + hd] = f2b(acc[i][n][e]);
                } else {
                    ushort4 pk;
                    pk.x = f2b(acc[i][n][0]); pk.y = f2b(acc[i][n][1]);
                    pk.z = f2b(acc[i][n][2]); pk.w = f2b(acc[i][n][3]);
                    *(ushort4*)&ovT[((b * NH + h) * HD + hd) * TT + t] = pk;
                }
            }
        }
    } else {
#pragma unroll
        for (int i = 0; i < 4; i++) {
            const long r = row0 + wr * 64 + i * 16 + g * 4;
#pragma unroll
            for (int n = 0; n < 4; n++) {
                const long c = col0 + wc * 64 + n * 16 + l15;
#pragma unroll
                for (int e = 0; e < 4; e++)
                    of[(r + e) * (long)N + c] = acc[i][n][e];
            }
        }
    }
}

// ---------------- flash attention ----------------
// grid (T/128, B*H), 256 threads (4 waves x 32 queries). KV tiles of 64 keys.

__global__ __launch_bounds__(256, 2)
void attn_fwd(const u16* __restrict__ gq, const u16* __restrict__ gk,
              const u16* __restrict__ gvT, u16* __restrict__ o)
{
    __shared__ __align__(16) u16 Klds[64 * 64];   // [key][hd]
    __shared__ __align__(16) u16 Vlds[64 * 64];   // [hd][key]
    __shared__ __align__(16) u16 Plds[4][32 * 64]; // per-wave [q][key]

    const int tid = threadIdx.x;
    const int wv = tid >> 6, lane = tid & 63, l15 = lane & 15, g = lane >> 4;
    const int bh = blockIdx.y;
    const int q0 = blockIdx.x * 128;
    const int qw0 = q0 + wv * 32;

    const u16* qbase = gq + (size_t)bh * TT * HD;
    const u16* kbase = gk + (size_t)bh * TT * HD;
    const u16* vbase = gvT + (size_t)bh * HD * TT;

    const float NEG_INF = -__builtin_inff();
    const f32x4 z4 = {0.f, 0.f, 0.f, 0.f};

    bf16x8 qf[2][2];
#pragma unroll
    for (int qi = 0; qi < 2; qi++)
#pragma unroll
        for (int hs = 0; hs < 2; hs++)
            qf[qi][hs] = *(const bf16x8*)(qbase + (size_t)(qw0 + qi * 16 + l15) * HD + hs * 32 + g * 8);

    f32x4 o_acc[2][4];
    float m[2][4], ls[2][4];
#pragma unroll
    for (int qi = 0; qi < 2; qi++) {
#pragma unroll
        for (int n = 0; n < 4; n++) o_acc[qi][n] = z4;
#pragma unroll
        for (int e = 0; e < 4; e++) { m[qi][e] = NEG_INF; ls[qi][e] = 0.f; }
    }

    const int nkt = q0 / 64 + 2;
    for (int kt = 0; kt < nkt; ++kt) {
        const int k0 = kt * 64;
        {
            const int c = tid, c2 = tid + 256;
            gload16(kbase + (size_t)(k0 + (c  >> 3)) * HD + (c  & 7) * 8, &Klds[c  * 8]);
            gload16(kbase + (size_t)(k0 + (c2 >> 3)) * HD + (c2 & 7) * 8, &Klds[c2 * 8]);
            gload16(vbase + (size_t)(c  >> 3) * TT + k0 + (c  & 7) * 8, &Vlds[c  * 8]);
            gload16(vbase + (size_t)(c2 >> 3) * TT + k0 + (c2 & 7) * 8, &Vlds[c2 * 8]);
        }
        __syncthreads();
        if (k0 <= qw0 + 31) {
            // QK^T : s[qi][kb], query = qw0+qi*16+4g+e, key = k0+kb*16+l15
            f32x4 s[2][4];
#pragma unroll
            for (int kb = 0; kb < 4; kb++) {
                bf16x8 kf0 = *(const bf16x8*)&Klds[(kb * 16 + l15) * 64 + 0  + g * 8];
                bf16x8 kf1 = *(const bf16x8*)&Klds[(kb * 16 + l15) * 64 + 32 + g * 8];
#pragma unroll
                for (int qi = 0; qi < 2; qi++) {
                    f32x4 t0 = __builtin_amdgcn_mfma_f32_16x16x32_bf16(qf[qi][0], kf0, z4, 0, 0, 0);
                    s[qi][kb] = __builtin_amdgcn_mfma_f32_16x16x32_bf16(qf[qi][1], kf1, t0, 0, 0, 0);
                }
            }
            if (k0 + 63 > qw0) {
#pragma unroll
                for (int qi = 0; qi < 2; qi++)
#pragma unroll
                    for (int kb = 0; kb < 4; kb++)
#pragma unroll
                        for (int e = 0; e < 4; e++) {
                            int qq = qw0 + qi * 16 + g * 4 + e;
                            int kk = k0 + kb * 16 + l15;
                            if (kk > qq) s[qi][kb][e] = NEG_INF;
                        }
            }
            // online softmax
#pragma unroll
            for (int qi = 0; qi < 2; qi++)
#pragma unroll
                for (int e = 0; e < 4; e++) {
                    float vm = fmaxf(fmaxf(s[qi][0][e], s[qi][1][e]), fmaxf(s[qi][2][e], s[qi][3][e]));
                    vm = fmaxf(vm, __shfl_xor(vm, 1));
                    vm = fmaxf(vm, __shfl_xor(vm, 2));
                    vm = fmaxf(vm, __shfl_xor(vm, 4));
                    vm = fmaxf(vm, __shfl_xor(vm, 8));
                    const float mn = fmaxf(m[qi][e], vm);
                    const float sc = __expf(m[qi][e] - mn);
                    m[qi][e] = mn;
                    float rs = 0.f;
#pragma unroll
                    for (int kb = 0; kb < 4; kb++) {
                        float pv = __expf(s[qi][kb][e] - mn);
                        rs += pv;
                        Plds[wv][(qi * 16 + g * 4 + e) * 64 + kb * 16 + l15] = f2b(pv);
                    }
                    rs += __shfl_xor(rs, 1);
                    rs += __shfl_xor(rs, 2);
                    rs += __shfl_xor(rs, 4);
                    rs += __shfl_xor(rs, 8);
                    ls[qi][e] = ls[qi][e] * sc + rs;
#pragma unroll
                    for (int n = 0; n < 4; n++) o_acc[qi][n][e] *= sc;
                }
            asm volatile("s_waitcnt lgkmcnt(0)" ::: "memory");
            // PV
#pragma unroll
            for (int ks = 0; ks < 2; ks++) {
                bf16x8 vf[4];
#pragma unroll
                for (int n = 0; n < 4; n++)
                    vf[n] = *(const bf16x8*)&Vlds[(n * 16 + l15) * 64 + ks * 32 + g * 8];
#pragma unroll
                for (int qi = 0; qi < 2; qi++) {
                    bf16x8 pf = *(const bf16x8*)&Plds[wv][(qi * 16 + l15) * 64 + ks * 32 + g * 8];
#pragma unroll
                    for (int n = 0; n < 4; n++)
                        o_acc[qi][n] = __builtin_amdgcn_mfma_f32_16x16x32_bf16(pf, vf[n], o_acc[qi][n], 0, 0, 0);
                }
            }
        }
        __syncthreads();
    }

    const int b = bh >> 4, h = bh & 15;
#pragma unroll
    for (int qi = 0; qi < 2; qi++)
#pragma unroll
        for (int e = 0; e < 4; e++) {
            const float inv = 1.f / ls[qi][e];
            const int t = qw0 + qi * 16 + g * 4 + e;
#pragma unroll
            for (int n = 0; n < 4; n++)
                o[((size_t)(b * TT + t)) * DD + h * HD + n * 16 + l15] = f2b(o_acc[qi][n][e] * inv);
        }
}

// ---------------- launch ----------------

extern "C" void kernel_launch(void* const* d_in, const int* in_sizes, int n_in,
                              void* d_out, int out_size, void* d_ws, size_t ws_size,
                              hipStream_t stream)
{
    const float* x     = (const float*)d_in[0];
    const float* w_qkv = (const float*)d_in[1];
    const float* w_o   = (const float*)d_in[2];
    float* out = (float*)d_out;
    char* ws = (char*)d_ws;

    u16* xb    = (u16*)(ws);                 // 8192x1024        16 MB
    u16* wqkvT = (u16*)(ws + 16777216);      // 3072x1024         6 MB
    u16* woT   = (u16*)(ws + 23068672);      // 1024x1024         2 MB
    u16* wsq   = (u16*)(ws + 25165824);      // [B,H,T,64]       16 MB
    u16* wsk   = (u16*)(ws + 41943040);      // [B,H,T,64]       16 MB
    u16* wsvT  = (u16*)(ws + 58720256);      // [B,H,64,T]       16 MB
    u16* attno = (u16*)(ws + 75497472);      // [B*T, D]         16 MB

    f32_to_bf16_vec<<<8192, 256, 0, stream>>>(x, xb, 2097152);
    dim3 tb(32, 8);
    transpose_f32_bf16<<<dim3(96, 32), tb, 0, stream>>>(w_qkv, wqkvT, 1024, 3072);
    transpose_f32_bf16<<<dim3(32, 32), tb, 0, stream>>>(w_o,   woT,   1024, 1024);

    gemm_bt<0><<<dim3(24, 64), 256, 0, stream>>>(xb, wqkvT, 8192, 3072, 1024, wsq, wsk, wsvT, nullptr);
    attn_fwd<<<dim3(16, 64), 256, 0, stream>>>(wsq, wsk, wsvT, attno);
    gemm_bt<1><<<dim3(8, 64), 256, 0, stream>>>(attno, woT, 8192, 1024, 1024, nullptr, nullptr, nullptr, out);
}

// Round 2
// 214.127 us; speedup vs baseline: 1.7275x; 1.7275x over previous
//
#include <hip/hip_runtime.h>
#include <hip/hip_bf16.h>
#include <stdint.h>

#define HD 64
#define NH 16
#define TT 2048
#define DD 1024

typedef uint16_t u16;
typedef __bf16 bf16_t;
typedef bf16_t bf16x8 __attribute__((ext_vector_type(8)));
typedef float f32x4 __attribute__((ext_vector_type(4)));

__device__ __forceinline__ u16 f2b(float f) {
    union { float f; uint32_t u; } v; v.f = f;
    uint32_t u = v.u;
    u += 0x7fff + ((u >> 16) & 1);   // RNE
    return (u16)(u >> 16);
}

__device__ __forceinline__ void gload16(const void* g, void* l) {
    __builtin_amdgcn_global_load_lds(
        (__attribute__((address_space(1))) void*)g,
        (__attribute__((address_space(3))) void*)l, 16, 0, 0);
}

// ---------------- converts ----------------

__global__ void f32_to_bf16_vec(const float* __restrict__ in, u16* __restrict__ out, int n4) {
    int i = blockIdx.x * 256 + threadIdx.x;
    if (i >= n4) return;
    float4 v = ((const float4*)in)[i];
    ushort4 r;
    r.x = f2b(v.x); r.y = f2b(v.y); r.z = f2b(v.z); r.w = f2b(v.w);
    ((ushort4*)out)[i] = r;
}

// out[c][r] = bf16(in[r][c]); R,C multiples of 32; block (32,8)
__global__ void transpose_f32_bf16(const float* __restrict__ in, u16* __restrict__ out, int R, int C) {
    __shared__ float tile[32][33];
    const int tx = threadIdx.x, ty = threadIdx.y;
    const int c0 = blockIdx.x * 32, r0 = blockIdx.y * 32;
#pragma unroll
    for (int j = 0; j < 32; j += 8)
        tile[ty + j][tx] = in[(size_t)(r0 + ty + j) * C + c0 + tx];
    __syncthreads();
#pragma unroll
    for (int j = 0; j < 32; j += 8)
        out[(size_t)(c0 + ty + j) * R + r0 + tx] = f2b(tile[tx][ty + j]);
}

// ---------------- GEMM C = A[M,K] * Bt[N,K]^T, bf16 in, f32 acc ----------------
// MODE 0: scatter epilogue -> q (x0.125), k, vT   (N=3072)
// MODE 1: plain f32 store to of[M,N]

template<int MODE>
__global__ __launch_bounds__(256, 2)
void gemm_bt(const u16* __restrict__ A, const u16* __restrict__ Bt,
             int M, int N, int K,
             u16* __restrict__ oq, u16* __restrict__ ok, u16* __restrict__ ovT,
             float* __restrict__ of)
{
    __shared__ __align__(16) u16 As[128 * 32];
    __shared__ __align__(16) u16 Bs[128 * 32];
    const int tid = threadIdx.x;
    const int lane = tid & 63, l15 = lane & 15, g = lane >> 4;
    const int wv = tid >> 6, wr = wv >> 1, wc = wv & 1;
    const long row0 = (long)blockIdx.y * 128;
    const long col0 = (long)blockIdx.x * 128;

    const int cA = tid, cB = tid + 256;
    const u16* a0 = A + (row0 + (cA >> 2)) * K + (cA & 3) * 8;
    const u16* a1 = A + (row0 + (cB >> 2)) * K + (cB & 3) * 8;
    const u16* b0 = Bt + (col0 + (cA >> 2)) * K + (cA & 3) * 8;
    const u16* b1 = Bt + (col0 + (cB >> 2)) * K + (cB & 3) * 8;

    const f32x4 z4 = {0.f, 0.f, 0.f, 0.f};
    f32x4 acc[4][4];
#pragma unroll
    for (int i = 0; i < 4; i++)
#pragma unroll
        for (int n = 0; n < 4; n++) acc[i][n] = z4;

    for (int k0 = 0; k0 < K; k0 += 32) {
        gload16(a0 + k0, &As[cA * 8]);
        gload16(a1 + k0, &As[cB * 8]);
        gload16(b0 + k0, &Bs[cA * 8]);
        gload16(b1 + k0, &Bs[cB * 8]);
        __syncthreads();
        bf16x8 af[4], bfr[4];
#pragma unroll
        for (int i = 0; i < 4; i++) af[i]  = *(const bf16x8*)&As[(wr * 64 + i * 16 + l15) * 32 + g * 8];
#pragma unroll
        for (int n = 0; n < 4; n++) bfr[n] = *(const bf16x8*)&Bs[(wc * 64 + n * 16 + l15) * 32 + g * 8];
#pragma unroll
        for (int i = 0; i < 4; i++)
#pragma unroll
            for (int n = 0; n < 4; n++)
                acc[i][n] = __builtin_amdgcn_mfma_f32_16x16x32_bf16(af[i], bfr[n], acc[i][n], 0, 0, 0);
        __syncthreads();
    }

    if (MODE == 0) {
        const int which = (int)(col0 >> 10);
        const long b = row0 >> 11;
#pragma unroll
        for (int i = 0; i < 4; i++) {
            const long r = row0 + wr * 64 + i * 16 + g * 4;
            const long t = r & (TT - 1);
#pragma unroll
            for (int n = 0; n < 4; n++) {
                const long c = col0 + wc * 64 + n * 16 + l15;
                const int h  = (int)((c >> 6) & 15);
                const int hd = (int)(c & 63);
                if (which == 0) {
#pragma unroll
                    for (int e = 0; e < 4; e++)
                        oq[((b * NH + h) * TT + t + e) * HD + hd] = f2b(acc[i][n][e] * 0.125f);
                } else if (which == 1) {
#pragma unroll
                    for (int e = 0; e < 4; e++)
                        ok[((b * NH + h) * TT + t + e) * HD + hd] = f2b(acc[i][n][e]);
                } else {
                    ushort4 pk;
                    pk.x = f2b(acc[i][n][0]); pk.y = f2b(acc[i][n][1]);
                    pk.z = f2b(acc[i][n][2]); pk.w = f2b(acc[i][n][3]);
                    *(ushort4*)&ovT[((b * NH + h) * HD + hd) * TT + t] = pk;
                }
            }
        }
    } else {
#pragma unroll
        for (int i = 0; i < 4; i++) {
            const long r = row0 + wr * 64 + i * 16 + g * 4;
#pragma unroll
            for (int n = 0; n < 4; n++) {
                const long c = col0 + wc * 64 + n * 16 + l15;
#pragma unroll
                for (int e = 0; e < 4; e++)
                    of[(r + e) * (long)N + c] = acc[i][n][e];
            }
        }
    }
}

// ---------------- flash attention ----------------
// 1D grid: blockIdx.x -> (qt heavy-first, bh). 256 threads (4 waves x 32 q).
// KV tiles of 64 keys, double-buffered, counted vmcnt, raw s_barrier.
// All LDS tiles XOR-swizzled: slot = chunk ^ (row&7) (chunk = 16B unit).

__global__ __launch_bounds__(256, 3)
void attn_fwd(const u16* __restrict__ gq, const u16* __restrict__ gk,
              const u16* __restrict__ gvT, u16* __restrict__ o)
{
    __shared__ __align__(16) u16 Klds[2][64 * 64];   // [key][hd] swizzled
    __shared__ __align__(16) u16 Vlds[2][64 * 64];   // [hd][key] swizzled
    __shared__ __align__(16) u16 Plds[4][32 * 64];   // per-wave [q][key] swizzled

    const int tid = threadIdx.x;
    const int wv = tid >> 6, lane = tid & 63, l15 = lane & 15, g = lane >> 4;
    const int bh = blockIdx.x & 63;
    const int qt = 15 - (blockIdx.x >> 6);       // heavy tiles dispatch first
    const int q0 = qt * 128;
    const int qw0 = q0 + wv * 32;

    const u16* qbase = gq + (size_t)bh * TT * HD;
    const u16* kbase = gk + (size_t)bh * TT * HD;
    const u16* vbase = gvT + (size_t)bh * HD * TT;

    const float NEG_INF = -__builtin_inff();
    const f32x4 z4 = {0.f, 0.f, 0.f, 0.f};

    bf16x8 qf[2][2];
#pragma unroll
    for (int qi = 0; qi < 2; qi++)
#pragma unroll
        for (int hs = 0; hs < 2; hs++)
            qf[qi][hs] = *(const bf16x8*)(qbase + (size_t)(qw0 + qi * 16 + l15) * HD + hs * 32 + g * 8);

    f32x4 o_acc[2][4];
    float m[2][4], ls[2][4];
#pragma unroll
    for (int qi = 0; qi < 2; qi++) {
#pragma unroll
        for (int n = 0; n < 4; n++) o_acc[qi][n] = z4;
#pragma unroll
        for (int e = 0; e < 4; e++) { m[qi][e] = NEG_INF; ls[qi][e] = 0.f; }
    }

    // staging lane roles (same for K and V): per call each thread loads 2 chunks of each
    const int r0_ = tid >> 3, c0_ = tid & 7;            // chunk (r0_, c0_)
    const int r1_ = (tid + 256) >> 3, c1_ = (tid + 256) & 7;

#define STAGE(buf, k0s)                                                                    \
    do {                                                                                   \
        gload16(kbase + (size_t)((k0s) + r0_) * HD + ((c0_ ^ (r0_ & 7)) * 8), &Klds[buf][tid * 8]);          \
        gload16(kbase + (size_t)((k0s) + r1_) * HD + ((c1_ ^ (r1_ & 7)) * 8), &Klds[buf][(tid + 256) * 8]);  \
        gload16(vbase + (size_t)r0_ * TT + (k0s) + ((c0_ ^ (r0_ & 7)) * 8), &Vlds[buf][tid * 8]);            \
        gload16(vbase + (size_t)r1_ * TT + (k0s) + ((c1_ ^ (r1_ & 7)) * 8), &Vlds[buf][(tid + 256) * 8]);    \
    } while (0)

    const int nkt = q0 / 64 + 2;
    STAGE(0, 0);
    for (int kt = 0; kt < nkt; ++kt) {
        const int k0 = kt * 64;
        const int cur = kt & 1;
        if (kt + 1 < nkt) {
            STAGE(cur ^ 1, k0 + 64);
            asm volatile("s_waitcnt vmcnt(4)" ::: "memory");  // tile kt's 4 loads done
        } else {
            asm volatile("s_waitcnt vmcnt(0)" ::: "memory");
        }
        __builtin_amdgcn_s_barrier();
        if (k0 <= qw0 + 31) {
            // QK^T : s[qi][kb], query = qw0+qi*16+4g+e, key = k0+kb*16+l15
            f32x4 s[2][4];
            const int sw = l15 & 7;   // row&7 for K rows (kb*16+l15) and V rows (n*16+l15)
#pragma unroll
            for (int kb = 0; kb < 4; kb++) {
                bf16x8 kf0 = *(const bf16x8*)&Klds[cur][(kb * 16 + l15) * 64 + ((g ^ sw) * 8)];
                bf16x8 kf1 = *(const bf16x8*)&Klds[cur][(kb * 16 + l15) * 64 + (((4 + g) ^ sw) * 8)];
#pragma unroll
                for (int qi = 0; qi < 2; qi++) {
                    f32x4 t0 = __builtin_amdgcn_mfma_f32_16x16x32_bf16(qf[qi][0], kf0, z4, 0, 0, 0);
                    s[qi][kb] = __builtin_amdgcn_mfma_f32_16x16x32_bf16(qf[qi][1], kf1, t0, 0, 0, 0);
                }
            }
            if (k0 + 63 > qw0) {
#pragma unroll
                for (int qi = 0; qi < 2; qi++)
#pragma unroll
                    for (int kb = 0; kb < 4; kb++)
#pragma unroll
                        for (int e = 0; e < 4; e++) {
                            int qq = qw0 + qi * 16 + g * 4 + e;
                            int kk = k0 + kb * 16 + l15;
                            if (kk > qq) s[qi][kb][e] = NEG_INF;
                        }
            }
            // online softmax (q-row = qi*16 + g*4 + e spread over lanes 0..15 of each 16-group? no:
            // row owner lanes: fixed (g,e) pair; reduce over l15 via xor 1,2,4,8)
#pragma unroll
            for (int qi = 0; qi < 2; qi++)
#pragma unroll
                for (int e = 0; e < 4; e++) {
                    float vm = fmaxf(fmaxf(s[qi][0][e], s[qi][1][e]), fmaxf(s[qi][2][e], s[qi][3][e]));
                    vm = fmaxf(vm, __shfl_xor(vm, 1));
                    vm = fmaxf(vm, __shfl_xor(vm, 2));
                    vm = fmaxf(vm, __shfl_xor(vm, 4));
                    vm = fmaxf(vm, __shfl_xor(vm, 8));
                    const float mn = fmaxf(m[qi][e], vm);
                    const float sc = __expf(m[qi][e] - mn);
                    m[qi][e] = mn;
                    const int prow = qi * 16 + g * 4 + e;     // row within wave's 32
                    const int psw = (g * 4 + e) & 7;          // row&7 for P
                    float rs = 0.f;
#pragma unroll
                    for (int kb = 0; kb < 4; kb++) {
                        float pv = __expf(s[qi][kb][e] - mn);
                        rs += pv;
                        const int chunk = kb * 2 + (l15 >> 3);
                        Plds[wv][prow * 64 + ((chunk ^ psw) * 8) + (l15 & 7)] = f2b(pv);
                    }
                    rs += __shfl_xor(rs, 1);
                    rs += __shfl_xor(rs, 2);
                    rs += __shfl_xor(rs, 4);
                    rs += __shfl_xor(rs, 8);
                    ls[qi][e] = ls[qi][e] * sc + rs;
#pragma unroll
                    for (int n = 0; n < 4; n++) o_acc[qi][n][e] *= sc;
                }
            asm volatile("s_waitcnt lgkmcnt(0)" ::: "memory");
            // PV
            const int sw2 = l15 & 7;
#pragma unroll
            for (int ks = 0; ks < 2; ks++) {
                bf16x8 vf[4];
#pragma unroll
                for (int n = 0; n < 4; n++)
                    vf[n] = *(const bf16x8*)&Vlds[cur][(n * 16 + l15) * 64 + (((ks * 4 + g) ^ sw2) * 8)];
#pragma unroll
                for (int qi = 0; qi < 2; qi++) {
                    bf16x8 pf = *(const bf16x8*)&Plds[wv][(qi * 16 + l15) * 64 + (((ks * 4 + g) ^ sw2) * 8)];
#pragma unroll
                    for (int n = 0; n < 4; n++)
                        o_acc[qi][n] = __builtin_amdgcn_mfma_f32_16x16x32_bf16(pf, vf[n], o_acc[qi][n], 0, 0, 0);
                }
            }
        }
        __builtin_amdgcn_s_barrier();
    }
#undef STAGE

    const int b = bh >> 4, h = bh & 15;
#pragma unroll
    for (int qi = 0; qi < 2; qi++)
#pragma unroll
        for (int e = 0; e < 4; e++) {
            const float inv = 1.f / ls[qi][e];
            const int t = qw0 + qi * 16 + g * 4 + e;
#pragma unroll
            for (int n = 0; n < 4; n++)
                o[((size_t)(b * TT + t)) * DD + h * HD + n * 16 + l15] = f2b(o_acc[qi][n][e] * inv);
        }
}

// ---------------- launch ----------------

extern "C" void kernel_launch(void* const* d_in, const int* in_sizes, int n_in,
                              void* d_out, int out_size, void* d_ws, size_t ws_size,
                              hipStream_t stream)
{
    const float* x     = (const float*)d_in[0];
    const float* w_qkv = (const float*)d_in[1];
    const float* w_o   = (const float*)d_in[2];
    float* out = (float*)d_out;
    char* ws = (char*)d_ws;

    u16* xb    = (u16*)(ws);                 // 8192x1024        16 MB
    u16* wqkvT = (u16*)(ws + 16777216);      // 3072x1024         6 MB
    u16* woT   = (u16*)(ws + 23068672);      // 1024x1024         2 MB
    u16* wsq   = (u16*)(ws + 25165824);      // [B,H,T,64]       16 MB
    u16* wsk   = (u16*)(ws + 41943040);      // [B,H,T,64]       16 MB
    u16* wsvT  = (u16*)(ws + 58720256);      // [B,H,64,T]       16 MB
    u16* attno = (u16*)(ws + 75497472);      // [B*T, D]         16 MB

    f32_to_bf16_vec<<<8192, 256, 0, stream>>>(x, xb, 2097152);
    dim3 tb(32, 8);
    transpose_f32_bf16<<<dim3(96, 32), tb, 0, stream>>>(w_qkv, wqkvT, 1024, 3072);
    transpose_f32_bf16<<<dim3(32, 32), tb, 0, stream>>>(w_o,   woT,   1024, 1024);

    gemm_bt<0><<<dim3(24, 64), 256, 0, stream>>>(xb, wqkvT, 8192, 3072, 1024, wsq, wsk, wsvT, nullptr);
    attn_fwd<<<1024, 256, 0, stream>>>(wsq, wsk, wsvT, attno);
    gemm_bt<1><<<dim3(8, 64), 256, 0, stream>>>(attno, woT, 8192, 1024, 1024, nullptr, nullptr, nullptr, out);
}

// Round 3
// 175.290 us; speedup vs baseline: 2.1102x; 1.2216x over previous
//
#include <hip/hip_runtime.h>
#include <hip/hip_bf16.h>
#include <stdint.h>

#define HD 64
#define NH 16
#define TT 2048
#define DD 1024

typedef uint16_t u16;
typedef __bf16 bf16_t;
typedef bf16_t bf16x8 __attribute__((ext_vector_type(8)));
typedef float f32x4 __attribute__((ext_vector_type(4)));

__device__ __forceinline__ u16 f2b(float f) {
    union { float f; uint32_t u; } v; v.f = f;
    uint32_t u = v.u;
    u += 0x7fff + ((u >> 16) & 1);   // RNE
    return (u16)(u >> 16);
}

__device__ __forceinline__ u16 b16(float f) {
    union { __bf16 h; u16 u; } c; c.h = (__bf16)f; return c.u;  // HW cvt (RNE)
}

__device__ __forceinline__ void gload16(const void* g, void* l) {
    __builtin_amdgcn_global_load_lds(
        (__attribute__((address_space(1))) void*)g,
        (__attribute__((address_space(3))) void*)l, 16, 0, 0);
}

// ---------------- converts ----------------

__global__ void f32_to_bf16_vec(const float* __restrict__ in, u16* __restrict__ out, int n4) {
    int i = blockIdx.x * 256 + threadIdx.x;
    if (i >= n4) return;
    float4 v = ((const float4*)in)[i];
    ushort4 r;
    r.x = f2b(v.x); r.y = f2b(v.y); r.z = f2b(v.z); r.w = f2b(v.w);
    ((ushort4*)out)[i] = r;
}

// out[c][r] = bf16(in[r][c]); R,C multiples of 32; block (32,8)
__global__ void transpose_f32_bf16(const float* __restrict__ in, u16* __restrict__ out, int R, int C) {
    __shared__ float tile[32][33];
    const int tx = threadIdx.x, ty = threadIdx.y;
    const int c0 = blockIdx.x * 32, r0 = blockIdx.y * 32;
#pragma unroll
    for (int j = 0; j < 32; j += 8)
        tile[ty + j][tx] = in[(size_t)(r0 + ty + j) * C + c0 + tx];
    __syncthreads();
#pragma unroll
    for (int j = 0; j < 32; j += 8)
        out[(size_t)(c0 + ty + j) * R + r0 + tx] = f2b(tile[tx][ty + j]);
}

// ---------------- GEMM C = A[M,K] * Bt[N,K]^T, bf16 in, f32 acc ----------------
// MODE 0: scatter epilogue -> q (x0.125), k, vT   (N=3072)
// MODE 1: plain f32 store to of[M,N]

template<int MODE>
__global__ __launch_bounds__(256, 2)
void gemm_bt(const u16* __restrict__ A, const u16* __restrict__ Bt,
             int M, int N, int K,
             u16* __restrict__ oq, u16* __restrict__ ok, u16* __restrict__ ovT,
             float* __restrict__ of)
{
    __shared__ __align__(16) u16 As[128 * 32];
    __shared__ __align__(16) u16 Bs[128 * 32];
    const int tid = threadIdx.x;
    const int lane = tid & 63, l15 = lane & 15, g = lane >> 4;
    const int wv = tid >> 6, wr = wv >> 1, wc = wv & 1;
    const long row0 = (long)blockIdx.y * 128;
    const long col0 = (long)blockIdx.x * 128;

    const int cA = tid, cB = tid + 256;
    const u16* a0 = A + (row0 + (cA >> 2)) * K + (cA & 3) * 8;
    const u16* a1 = A + (row0 + (cB >> 2)) * K + (cB & 3) * 8;
    const u16* b0 = Bt + (col0 + (cA >> 2)) * K + (cA & 3) * 8;
    const u16* b1 = Bt + (col0 + (cB >> 2)) * K + (cB & 3) * 8;

    const f32x4 z4 = {0.f, 0.f, 0.f, 0.f};
    f32x4 acc[4][4];
#pragma unroll
    for (int i = 0; i < 4; i++)
#pragma unroll
        for (int n = 0; n < 4; n++) acc[i][n] = z4;

    for (int k0 = 0; k0 < K; k0 += 32) {
        gload16(a0 + k0, &As[cA * 8]);
        gload16(a1 + k0, &As[cB * 8]);
        gload16(b0 + k0, &Bs[cA * 8]);
        gload16(b1 + k0, &Bs[cB * 8]);
        __syncthreads();
        bf16x8 af[4], bfr[4];
#pragma unroll
        for (int i = 0; i < 4; i++) af[i]  = *(const bf16x8*)&As[(wr * 64 + i * 16 + l15) * 32 + g * 8];
#pragma unroll
        for (int n = 0; n < 4; n++) bfr[n] = *(const bf16x8*)&Bs[(wc * 64 + n * 16 + l15) * 32 + g * 8];
#pragma unroll
        for (int i = 0; i < 4; i++)
#pragma unroll
            for (int n = 0; n < 4; n++)
                acc[i][n] = __builtin_amdgcn_mfma_f32_16x16x32_bf16(af[i], bfr[n], acc[i][n], 0, 0, 0);
        __syncthreads();
    }

    if (MODE == 0) {
        const int which = (int)(col0 >> 10);
        const long b = row0 >> 11;
#pragma unroll
        for (int i = 0; i < 4; i++) {
            const long r = row0 + wr * 64 + i * 16 + g * 4;
            const long t = r & (TT - 1);
#pragma unroll
            for (int n = 0; n < 4; n++) {
                const long c = col0 + wc * 64 + n * 16 + l15;
                const int h  = (int)((c >> 6) & 15);
                const int hd = (int)(c & 63);
                if (which == 0) {
#pragma unroll
                    for (int e = 0; e < 4; e++)
                        oq[((b * NH + h) * TT + t + e) * HD + hd] = f2b(acc[i][n][e] * 0.125f);
                } else if (which == 1) {
#pragma unroll
                    for (int e = 0; e < 4; e++)
                        ok[((b * NH + h) * TT + t + e) * HD + hd] = f2b(acc[i][n][e]);
                } else {
                    ushort4 pk;
                    pk.x = f2b(acc[i][n][0]); pk.y = f2b(acc[i][n][1]);
                    pk.z = f2b(acc[i][n][2]); pk.w = f2b(acc[i][n][3]);
                    *(ushort4*)&ovT[((b * NH + h) * HD + hd) * TT + t] = pk;
                }
            }
        }
    } else {
#pragma unroll
        for (int i = 0; i < 4; i++) {
            const long r = row0 + wr * 64 + i * 16 + g * 4;
#pragma unroll
            for (int n = 0; n < 4; n++) {
                const long c = col0 + wc * 64 + n * 16 + l15;
#pragma unroll
                for (int e = 0; e < 4; e++)
                    of[(r + e) * (long)N + c] = acc[i][n][e];
            }
        }
    }
}

// ---------------- flash attention ----------------
// 1D grid: blockIdx.x -> (qt heavy-first, bh). 256 threads (4 waves x 32 q).
// KV tiles of 64 keys, double-buffered, counted vmcnt, raw s_barrier.
// K/V LDS XOR-swizzled (chunk ^ row&7, via pre-swizzled global src).
// QK^T computed SWAPPED: s = mfma(K,Q) -> q = lane&15, key = g*4+e (in-lane row).
// P repacked through per-wave LDS as 8B granules, granule ^ (l15&15) swizzle.

__global__ __launch_bounds__(256, 3)
void attn_fwd(const u16* __restrict__ gq, const u16* __restrict__ gk,
              const u16* __restrict__ gvT, u16* __restrict__ o)
{
    __shared__ __align__(16) u16 Klds[2][64 * 64];   // [key][hd] swizzled
    __shared__ __align__(16) u16 Vlds[2][64 * 64];   // [hd][key] swizzled
    __shared__ __align__(16) u16 Plds[4][32 * 64];   // per-wave [q][16 x 8B granules]

    const int tid = threadIdx.x;
    const int wv = tid >> 6, lane = tid & 63, l15 = lane & 15, g = lane >> 4;
    const int bh = blockIdx.x & 63;
    const int qt = 15 - (blockIdx.x >> 6);       // heavy tiles dispatch first
    const int q0 = qt * 128;
    const int qw0 = q0 + wv * 32;

    const u16* qbase = gq + (size_t)bh * TT * HD;
    const u16* kbase = gk + (size_t)bh * TT * HD;
    const u16* vbase = gvT + (size_t)bh * HD * TT;

    const float NEG_INF = -__builtin_inff();
    const f32x4 z4 = {0.f, 0.f, 0.f, 0.f};

    bf16x8 qf[2][2];
#pragma unroll
    for (int qi = 0; qi < 2; qi++)
#pragma unroll
        for (int hs = 0; hs < 2; hs++)
            qf[qi][hs] = *(const bf16x8*)(qbase + (size_t)(qw0 + qi * 16 + l15) * HD + hs * 32 + g * 8);

    f32x4 o_acc[2][4];
    float m[2], ls[2];
#pragma unroll
    for (int qi = 0; qi < 2; qi++) {
#pragma unroll
        for (int n = 0; n < 4; n++) o_acc[qi][n] = z4;
        m[qi] = NEG_INF; ls[qi] = 0.f;
    }

    // staging lane roles (same for K and V): per call each thread loads 2 chunks of each
    const int r0_ = tid >> 3, c0_ = tid & 7;            // chunk (r0_, c0_)
    const int r1_ = (tid + 256) >> 3, c1_ = (tid + 256) & 7;

#define STAGE(buf, k0s)                                                                    \
    do {                                                                                   \
        gload16(kbase + (size_t)((k0s) + r0_) * HD + ((c0_ ^ (r0_ & 7)) * 8), &Klds[buf][tid * 8]);          \
        gload16(kbase + (size_t)((k0s) + r1_) * HD + ((c1_ ^ (r1_ & 7)) * 8), &Klds[buf][(tid + 256) * 8]);  \
        gload16(vbase + (size_t)r0_ * TT + (k0s) + ((c0_ ^ (r0_ & 7)) * 8), &Vlds[buf][tid * 8]);            \
        gload16(vbase + (size_t)r1_ * TT + (k0s) + ((c1_ ^ (r1_ & 7)) * 8), &Vlds[buf][(tid + 256) * 8]);    \
    } while (0)

    const int nkt = q0 / 64 + 2;
    STAGE(0, 0);
    for (int kt = 0; kt < nkt; ++kt) {
        const int k0 = kt * 64;
        const int cur = kt & 1;
        if (kt + 1 < nkt) {
            STAGE(cur ^ 1, k0 + 64);
            asm volatile("s_waitcnt vmcnt(4)" ::: "memory");  // tile kt's 4 loads done
        } else {
            asm volatile("s_waitcnt vmcnt(0)" ::: "memory");
        }
        __builtin_amdgcn_s_barrier();
        if (k0 <= qw0 + 31) {
            const int sw = l15 & 7;   // row&7 for K rows (kb*16+l15) and V rows (n*16+l15)
            // swapped QK^T: s2[qi][kb]: q = qi*16 + l15, key = k0 + kb*16 + g*4 + e
            f32x4 s2[2][4];
            __builtin_amdgcn_s_setprio(1);
#pragma unroll
            for (int kb = 0; kb < 4; kb++) {
                bf16x8 kf0 = *(const bf16x8*)&Klds[cur][(kb * 16 + l15) * 64 + ((g ^ sw) * 8)];
                bf16x8 kf1 = *(const bf16x8*)&Klds[cur][(kb * 16 + l15) * 64 + (((4 + g) ^ sw) * 8)];
#pragma unroll
                for (int qi = 0; qi < 2; qi++) {
                    f32x4 t0 = __builtin_amdgcn_mfma_f32_16x16x32_bf16(kf0, qf[qi][0], z4, 0, 0, 0);
                    s2[qi][kb] = __builtin_amdgcn_mfma_f32_16x16x32_bf16(kf1, qf[qi][1], t0, 0, 0, 0);
                }
            }
            __builtin_amdgcn_s_setprio(0);
            if (k0 + 63 > qw0) {
#pragma unroll
                for (int qi = 0; qi < 2; qi++)
#pragma unroll
                    for (int kb = 0; kb < 4; kb++)
#pragma unroll
                        for (int e = 0; e < 4; e++) {
                            const int kk = k0 + kb * 16 + g * 4 + e;
                            const int qq = qw0 + qi * 16 + l15;
                            if (kk > qq) s2[qi][kb][e] = NEG_INF;
                        }
            }
            // in-register online softmax (q = l15 per lane)
#pragma unroll
            for (int qi = 0; qi < 2; qi++) {
                f32x4 mx = s2[qi][0];
#pragma unroll
                for (int kb = 1; kb < 4; kb++)
#pragma unroll
                    for (int e = 0; e < 4; e++) mx[e] = fmaxf(mx[e], s2[qi][kb][e]);
                float pmax = fmaxf(fmaxf(mx[0], mx[1]), fmaxf(mx[2], mx[3]));
                pmax = fmaxf(pmax, __shfl_xor(pmax, 16));
                pmax = fmaxf(pmax, __shfl_xor(pmax, 32));
                float mn = m[qi];
                const int resc = !__all(pmax <= mn + 8.f);   // T13 defer-max
                if (resc) {
                    const float mold = mn;
                    mn = fmaxf(mold, pmax);
                    m[qi] = mn;
                    const float sc = __expf(mold - mn);
                    ls[qi] *= sc;
#pragma unroll
                    for (int e = 0; e < 4; e++) {
                        const float sce = __shfl(sc, (lane & 48) + (((lane >> 4) & 3) << 2) + e);
#pragma unroll
                        for (int n = 0; n < 4; n++) o_acc[qi][n][e] *= sce;
                    }
                }
                const int prow = qi * 16 + l15;
                u16* pb = &Plds[wv][prow * 64];
                float rsum = 0.f;
#pragma unroll
                for (int kb = 0; kb < 4; kb++) {
                    const float p0 = __expf(s2[qi][kb][0] - mn);
                    const float p1 = __expf(s2[qi][kb][1] - mn);
                    const float p2 = __expf(s2[qi][kb][2] - mn);
                    const float p3 = __expf(s2[qi][kb][3] - mn);
                    rsum += (p0 + p1) + (p2 + p3);
                    ushort4 pk;
                    pk.x = b16(p0); pk.y = b16(p1); pk.z = b16(p2); pk.w = b16(p3);
                    *(ushort4*)&pb[(((kb << 2) + g) ^ l15) * 4] = pk;
                }
                rsum += __shfl_xor(rsum, 16);
                rsum += __shfl_xor(rsum, 32);
                ls[qi] += rsum;
            }
            // PV: A = P (row q=l15, keys g*8+j), B = V^T
#pragma unroll
            for (int ks = 0; ks < 2; ks++) {
                bf16x8 vf[4];
#pragma unroll
                for (int n = 0; n < 4; n++)
                    vf[n] = *(const bf16x8*)&Vlds[cur][(n * 16 + l15) * 64 + (((ks * 4 + g) ^ sw) * 8)];
                __builtin_amdgcn_s_setprio(1);
#pragma unroll
                for (int qi = 0; qi < 2; qi++) {
                    const u16* pb = &Plds[wv][(qi * 16 + l15) * 64];
                    const int G0 = ((ks << 3) + (g << 1)) ^ l15;
                    const int G1 = ((ks << 3) + (g << 1) + 1) ^ l15;
                    const uint2 ra = *(const uint2*)&pb[G0 * 4];
                    const uint2 rb = *(const uint2*)&pb[G1 * 4];
                    union { uint32_t w[4]; bf16x8 v; } pu;
                    pu.w[0] = ra.x; pu.w[1] = ra.y; pu.w[2] = rb.x; pu.w[3] = rb.y;
#pragma unroll
                    for (int n = 0; n < 4; n++)
                        o_acc[qi][n] = __builtin_amdgcn_mfma_f32_16x16x32_bf16(pu.v, vf[n], o_acc[qi][n], 0, 0, 0);
                }
                __builtin_amdgcn_s_setprio(0);
            }
        }
        __builtin_amdgcn_s_barrier();
    }
#undef STAGE

    const int b = bh >> 4, h = bh & 15;
#pragma unroll
    for (int qi = 0; qi < 2; qi++) {
        const float linv = 1.f / ls[qi];
#pragma unroll
        for (int e = 0; e < 4; e++) {
            const float inv = __shfl(linv, (lane & 48) + (((lane >> 4) & 3) << 2) + e);
            const int t = qw0 + qi * 16 + g * 4 + e;
#pragma unroll
            for (int n = 0; n < 4; n++)
                o[((size_t)(b * TT + t)) * DD + h * HD + n * 16 + l15] = f2b(o_acc[qi][n][e] * inv);
        }
    }
}

// ---------------- launch ----------------

extern "C" void kernel_launch(void* const* d_in, const int* in_sizes, int n_in,
                              void* d_out, int out_size, void* d_ws, size_t ws_size,
                              hipStream_t stream)
{
    const float* x     = (const float*)d_in[0];
    const float* w_qkv = (const float*)d_in[1];
    const float* w_o   = (const float*)d_in[2];
    float* out = (float*)d_out;
    char* ws = (char*)d_ws;

    u16* xb    = (u16*)(ws);                 // 8192x1024        16 MB
    u16* wqkvT = (u16*)(ws + 16777216);      // 3072x1024         6 MB
    u16* woT   = (u16*)(ws + 23068672);      // 1024x1024         2 MB
    u16* wsq   = (u16*)(ws + 25165824);      // [B,H,T,64]       16 MB
    u16* wsk   = (u16*)(ws + 41943040);      // [B,H,T,64]       16 MB
    u16* wsvT  = (u16*)(ws + 58720256);      // [B,H,64,T]       16 MB
    u16* attno = (u16*)(ws + 75497472);      // [B*T, D]         16 MB

    f32_to_bf16_vec<<<8192, 256, 0, stream>>>(x, xb, 2097152);
    dim3 tb(32, 8);
    transpose_f32_bf16<<<dim3(96, 32), tb, 0, stream>>>(w_qkv, wqkvT, 1024, 3072);
    transpose_f32_bf16<<<dim3(32, 32), tb, 0, stream>>>(w_o,   woT,   1024, 1024);

    gemm_bt<0><<<dim3(24, 64), 256, 0, stream>>>(xb, wqkvT, 8192, 3072, 1024, wsq, wsk, wsvT, nullptr);
    attn_fwd<<<1024, 256, 0, stream>>>(wsq, wsk, wsvT, attno);
    gemm_bt<1><<<dim3(8, 64), 256, 0, stream>>>(attno, woT, 8192, 1024, 1024, nullptr, nullptr, nullptr, out);
}

// Round 4
// 174.007 us; speedup vs baseline: 2.1258x; 1.0074x over previous
//
#include <hip/hip_runtime.h>
#include <hip/hip_bf16.h>
#include <stdint.h>

#define HD 64
#define NH 16
#define TT 2048
#define DD 1024

typedef uint16_t u16;
typedef __bf16 bf16_t;
typedef bf16_t bf16x8 __attribute__((ext_vector_type(8)));
typedef float f32x4 __attribute__((ext_vector_type(4)));

__device__ __forceinline__ u16 f2b(float f) {
    union { float f; uint32_t u; } v; v.f = f;
    uint32_t u = v.u;
    u += 0x7fff + ((u >> 16) & 1);   // RNE
    return (u16)(u >> 16);
}

__device__ __forceinline__ u16 b16(float f) {
    union { __bf16 h; u16 u; } c; c.h = (__bf16)f; return c.u;  // HW cvt (RNE)
}

__device__ __forceinline__ void gload16(const void* g, void* l) {
    __builtin_amdgcn_global_load_lds(
        (__attribute__((address_space(1))) void*)g,
        (__attribute__((address_space(3))) void*)l, 16, 0, 0);
}

// ---------------- converts ----------------

__global__ void f32_to_bf16_vec(const float* __restrict__ in, u16* __restrict__ out, int n4) {
    int i = blockIdx.x * 256 + threadIdx.x;
    if (i >= n4) return;
    float4 v = ((const float4*)in)[i];
    ushort4 r;
    r.x = f2b(v.x); r.y = f2b(v.y); r.z = f2b(v.z); r.w = f2b(v.w);
    ((ushort4*)out)[i] = r;
}

// out[c][r] = bf16(in[r][c]); R,C multiples of 32; block (32,8)
__global__ void transpose_f32_bf16(const float* __restrict__ in, u16* __restrict__ out, int R, int C) {
    __shared__ float tile[32][33];
    const int tx = threadIdx.x, ty = threadIdx.y;
    const int c0 = blockIdx.x * 32, r0 = blockIdx.y * 32;
#pragma unroll
    for (int j = 0; j < 32; j += 8)
        tile[ty + j][tx] = in[(size_t)(r0 + ty + j) * C + c0 + tx];
    __syncthreads();
#pragma unroll
    for (int j = 0; j < 32; j += 8)
        out[(size_t)(c0 + ty + j) * R + r0 + tx] = f2b(tile[tx][ty + j]);
}

// ---------------- GEMM C = A[M,K] * Bt[N,K]^T, bf16 in, f32 acc ----------------
// LDS tiles [128][32] bf16, chunk (16B) XOR-swizzled by (row>>1)&3.
// Double-buffered, counted vmcnt(4), raw s_barrier.
// MODE 0: scatter epilogue -> q (x0.125), k, vT   (N=3072)
// MODE 1: plain f32 store to of[M,N]

template<int MODE>
__global__ __launch_bounds__(256, 3)
void gemm_bt(const u16* __restrict__ A, const u16* __restrict__ Bt,
             int M, int N, int K,
             u16* __restrict__ oq, u16* __restrict__ ok, u16* __restrict__ ovT,
             float* __restrict__ of)
{
    __shared__ __align__(16) u16 As[2][128 * 32];
    __shared__ __align__(16) u16 Bs[2][128 * 32];
    const int tid = threadIdx.x;
    const int lane = tid & 63, l15 = lane & 15, g = lane >> 4;
    const int wv = tid >> 6, wr = wv >> 1, wc = wv & 1;
    const long row0 = (long)blockIdx.y * 128;
    const long col0 = (long)blockIdx.x * 128;

    const int cA = tid, cB = tid + 256;
    // staging source: chunk XOR-swizzled by (row>>1)&3 (row = c>>2, chunk = c&3)
    const u16* a0 = A + (row0 + (cA >> 2)) * K + (((cA & 3) ^ ((cA >> 3) & 3)) * 8);
    const u16* a1 = A + (row0 + (cB >> 2)) * K + (((cB & 3) ^ ((cB >> 3) & 3)) * 8);
    const u16* b0 = Bt + (col0 + (cA >> 2)) * K + (((cA & 3) ^ ((cA >> 3) & 3)) * 8);
    const u16* b1 = Bt + (col0 + (cB >> 2)) * K + (((cB & 3) ^ ((cB >> 3) & 3)) * 8);

    const f32x4 z4 = {0.f, 0.f, 0.f, 0.f};
    f32x4 acc[4][4];
#pragma unroll
    for (int i = 0; i < 4; i++)
#pragma unroll
        for (int n = 0; n < 4; n++) acc[i][n] = z4;

    const int swz = (l15 >> 1) & 3;   // read-side chunk XOR (row>>1)&3 == (l15>>1)&3

#define GSTAGE(buf, k0s)                          \
    do {                                          \
        gload16(a0 + (k0s), &As[buf][cA * 8]);    \
        gload16(a1 + (k0s), &As[buf][cB * 8]);    \
        gload16(b0 + (k0s), &Bs[buf][cA * 8]);    \
        gload16(b1 + (k0s), &Bs[buf][cB * 8]);    \
    } while (0)

    const int niter = K >> 5;
    GSTAGE(0, 0);
    for (int it = 0; it < niter; ++it) {
        const int cur = it & 1;
        if (it + 1 < niter) {
            GSTAGE(cur ^ 1, (it + 1) * 32);
            asm volatile("s_waitcnt vmcnt(4)" ::: "memory");  // tile it's 4 loads done
        } else {
            asm volatile("s_waitcnt vmcnt(0)" ::: "memory");
        }
        __builtin_amdgcn_s_barrier();
        bf16x8 af[4], bfr[4];
#pragma unroll
        for (int i = 0; i < 4; i++)
            af[i]  = *(const bf16x8*)&As[cur][(wr * 64 + i * 16 + l15) * 32 + ((g ^ swz) << 3)];
#pragma unroll
        for (int n = 0; n < 4; n++)
            bfr[n] = *(const bf16x8*)&Bs[cur][(wc * 64 + n * 16 + l15) * 32 + ((g ^ swz) << 3)];
        __builtin_amdgcn_s_setprio(1);
#pragma unroll
        for (int i = 0; i < 4; i++)
#pragma unroll
            for (int n = 0; n < 4; n++)
                acc[i][n] = __builtin_amdgcn_mfma_f32_16x16x32_bf16(af[i], bfr[n], acc[i][n], 0, 0, 0);
        __builtin_amdgcn_s_setprio(0);
        __builtin_amdgcn_s_barrier();
    }
#undef GSTAGE

    if (MODE == 0) {
        const int which = (int)(col0 >> 10);
        const long b = row0 >> 11;
#pragma unroll
        for (int i = 0; i < 4; i++) {
            const long r = row0 + wr * 64 + i * 16 + g * 4;
            const long t = r & (TT - 1);
#pragma unroll
            for (int n = 0; n < 4; n++) {
                const long c = col0 + wc * 64 + n * 16 + l15;
                const int h  = (int)((c >> 6) & 15);
                const int hd = (int)(c & 63);
                if (which == 0) {
#pragma unroll
                    for (int e = 0; e < 4; e++)
                        oq[((b * NH + h) * TT + t + e) * HD + hd] = f2b(acc[i][n][e] * 0.125f);
                } else if (which == 1) {
#pragma unroll
                    for (int e = 0; e < 4; e++)
                        ok[((b * NH + h) * TT + t + e) * HD + hd] = f2b(acc[i][n][e]);
                } else {
                    ushort4 pk;
                    pk.x = f2b(acc[i][n][0]); pk.y = f2b(acc[i][n][1]);
                    pk.z = f2b(acc[i][n][2]); pk.w = f2b(acc[i][n][3]);
                    *(ushort4*)&ovT[((b * NH + h) * HD + hd) * TT + t] = pk;
                }
            }
        }
    } else {
#pragma unroll
        for (int i = 0; i < 4; i++) {
            const long r = row0 + wr * 64 + i * 16 + g * 4;
#pragma unroll
            for (int n = 0; n < 4; n++) {
                const long c = col0 + wc * 64 + n * 16 + l15;
#pragma unroll
                for (int e = 0; e < 4; e++)
                    of[(r + e) * (long)N + c] = acc[i][n][e];
            }
        }
    }
}

// ---------------- flash attention ----------------
// 1D grid: blockIdx.x -> (qt heavy-first, bh). 256 threads (4 waves x 32 q).
// KV tiles of 64 keys, double-buffered, counted vmcnt, raw s_barrier.
// K/V LDS XOR-swizzled (chunk ^ row&7, via pre-swizzled global src).
// QK^T computed SWAPPED: s = mfma(K,Q) -> q = lane&15, key = g*4+e (in-lane row).
// P repacked through per-wave LDS as 8B granules, granule ^ (l15&15) swizzle.

__global__ __launch_bounds__(256, 3)
void attn_fwd(const u16* __restrict__ gq, const u16* __restrict__ gk,
              const u16* __restrict__ gvT, u16* __restrict__ o)
{
    __shared__ __align__(16) u16 Klds[2][64 * 64];   // [key][hd] swizzled
    __shared__ __align__(16) u16 Vlds[2][64 * 64];   // [hd][key] swizzled
    __shared__ __align__(16) u16 Plds[4][32 * 64];   // per-wave [q][16 x 8B granules]

    const int tid = threadIdx.x;
    const int wv = tid >> 6, lane = tid & 63, l15 = lane & 15, g = lane >> 4;
    const int bh = blockIdx.x & 63;
    const int qt = 15 - (blockIdx.x >> 6);       // heavy tiles dispatch first
    const int q0 = qt * 128;
    const int qw0 = q0 + wv * 32;

    const u16* qbase = gq + (size_t)bh * TT * HD;
    const u16* kbase = gk + (size_t)bh * TT * HD;
    const u16* vbase = gvT + (size_t)bh * HD * TT;

    const float NEG_INF = -__builtin_inff();
    const f32x4 z4 = {0.f, 0.f, 0.f, 0.f};

    bf16x8 qf[2][2];
#pragma unroll
    for (int qi = 0; qi < 2; qi++)
#pragma unroll
        for (int hs = 0; hs < 2; hs++)
            qf[qi][hs] = *(const bf16x8*)(qbase + (size_t)(qw0 + qi * 16 + l15) * HD + hs * 32 + g * 8);

    f32x4 o_acc[2][4];
    float m[2], ls[2];
#pragma unroll
    for (int qi = 0; qi < 2; qi++) {
#pragma unroll
        for (int n = 0; n < 4; n++) o_acc[qi][n] = z4;
        m[qi] = NEG_INF; ls[qi] = 0.f;
    }

    // staging lane roles (same for K and V): per call each thread loads 2 chunks of each
    const int r0_ = tid >> 3, c0_ = tid & 7;            // chunk (r0_, c0_)
    const int r1_ = (tid + 256) >> 3, c1_ = (tid + 256) & 7;

#define STAGE(buf, k0s)                                                                    \
    do {                                                                                   \
        gload16(kbase + (size_t)((k0s) + r0_) * HD + ((c0_ ^ (r0_ & 7)) * 8), &Klds[buf][tid * 8]);          \
        gload16(kbase + (size_t)((k0s) + r1_) * HD + ((c1_ ^ (r1_ & 7)) * 8), &Klds[buf][(tid + 256) * 8]);  \
        gload16(vbase + (size_t)r0_ * TT + (k0s) + ((c0_ ^ (r0_ & 7)) * 8), &Vlds[buf][tid * 8]);            \
        gload16(vbase + (size_t)r1_ * TT + (k0s) + ((c1_ ^ (r1_ & 7)) * 8), &Vlds[buf][(tid + 256) * 8]);    \
    } while (0)

    const int nkt = q0 / 64 + 2;
    STAGE(0, 0);
    for (int kt = 0; kt < nkt; ++kt) {
        const int k0 = kt * 64;
        const int cur = kt & 1;
        if (kt + 1 < nkt) {
            STAGE(cur ^ 1, k0 + 64);
            asm volatile("s_waitcnt vmcnt(4)" ::: "memory");  // tile kt's 4 loads done
        } else {
            asm volatile("s_waitcnt vmcnt(0)" ::: "memory");
        }
        __builtin_amdgcn_s_barrier();
        if (k0 <= qw0 + 31) {
            const int sw = l15 & 7;   // row&7 for K rows (kb*16+l15) and V rows (n*16+l15)
            // swapped QK^T: s2[qi][kb]: q = qi*16 + l15, key = k0 + kb*16 + g*4 + e
            f32x4 s2[2][4];
            __builtin_amdgcn_s_setprio(1);
#pragma unroll
            for (int kb = 0; kb < 4; kb++) {
                bf16x8 kf0 = *(const bf16x8*)&Klds[cur][(kb * 16 + l15) * 64 + ((g ^ sw) * 8)];
                bf16x8 kf1 = *(const bf16x8*)&Klds[cur][(kb * 16 + l15) * 64 + (((4 + g) ^ sw) * 8)];
#pragma unroll
                for (int qi = 0; qi < 2; qi++) {
                    f32x4 t0 = __builtin_amdgcn_mfma_f32_16x16x32_bf16(kf0, qf[qi][0], z4, 0, 0, 0);
                    s2[qi][kb] = __builtin_amdgcn_mfma_f32_16x16x32_bf16(kf1, qf[qi][1], t0, 0, 0, 0);
                }
            }
            __builtin_amdgcn_s_setprio(0);
            if (k0 + 63 > qw0) {
#pragma unroll
                for (int qi = 0; qi < 2; qi++)
#pragma unroll
                    for (int kb = 0; kb < 4; kb++)
#pragma unroll
                        for (int e = 0; e < 4; e++) {
                            const int kk = k0 + kb * 16 + g * 4 + e;
                            const int qq = qw0 + qi * 16 + l15;
                            if (kk > qq) s2[qi][kb][e] = NEG_INF;
                        }
            }
            // in-register online softmax (q = l15 per lane)
#pragma unroll
            for (int qi = 0; qi < 2; qi++) {
                f32x4 mx = s2[qi][0];
#pragma unroll
                for (int kb = 1; kb < 4; kb++)
#pragma unroll
                    for (int e = 0; e < 4; e++) mx[e] = fmaxf(mx[e], s2[qi][kb][e]);
                float pmax = fmaxf(fmaxf(mx[0], mx[1]), fmaxf(mx[2], mx[3]));
                pmax = fmaxf(pmax, __shfl_xor(pmax, 16));
                pmax = fmaxf(pmax, __shfl_xor(pmax, 32));
                float mn = m[qi];
                const int resc = !__all(pmax <= mn + 8.f);   // T13 defer-max
                if (resc) {
                    const float mold = mn;
                    mn = fmaxf(mold, pmax);
                    m[qi] = mn;
                    const float sc = __expf(mold - mn);
                    ls[qi] *= sc;
#pragma unroll
                    for (int e = 0; e < 4; e++) {
                        const float sce = __shfl(sc, (lane & 48) + (((lane >> 4) & 3) << 2) + e);
#pragma unroll
                        for (int n = 0; n < 4; n++) o_acc[qi][n][e] *= sce;
                    }
                }
                const int prow = qi * 16 + l15;
                u16* pb = &Plds[wv][prow * 64];
                float rsum = 0.f;
#pragma unroll
                for (int kb = 0; kb < 4; kb++) {
                    const float p0 = __expf(s2[qi][kb][0] - mn);
                    const float p1 = __expf(s2[qi][kb][1] - mn);
                    const float p2 = __expf(s2[qi][kb][2] - mn);
                    const float p3 = __expf(s2[qi][kb][3] - mn);
                    rsum += (p0 + p1) + (p2 + p3);
                    ushort4 pk;
                    pk.x = b16(p0); pk.y = b16(p1); pk.z = b16(p2); pk.w = b16(p3);
                    *(ushort4*)&pb[(((kb << 2) + g) ^ l15) * 4] = pk;
                }
                rsum += __shfl_xor(rsum, 16);
                rsum += __shfl_xor(rsum, 32);
                ls[qi] += rsum;
            }
            // PV: A = P (row q=l15, keys g*8+j), B = V^T
#pragma unroll
            for (int ks = 0; ks < 2; ks++) {
                bf16x8 vf[4];
#pragma unroll
                for (int n = 0; n < 4; n++)
                    vf[n] = *(const bf16x8*)&Vlds[cur][(n * 16 + l15) * 64 + (((ks * 4 + g) ^ sw) * 8)];
                __builtin_amdgcn_s_setprio(1);
#pragma unroll
                for (int qi = 0; qi < 2; qi++) {
                    const u16* pb = &Plds[wv][(qi * 16 + l15) * 64];
                    const int G0 = ((ks << 3) + (g << 1)) ^ l15;
                    const int G1 = ((ks << 3) + (g << 1) + 1) ^ l15;
                    const uint2 ra = *(const uint2*)&pb[G0 * 4];
                    const uint2 rb = *(const uint2*)&pb[G1 * 4];
                    union { uint32_t w[4]; bf16x8 v; } pu;
                    pu.w[0] = ra.x; pu.w[1] = ra.y; pu.w[2] = rb.x; pu.w[3] = rb.y;
#pragma unroll
                    for (int n = 0; n < 4; n++)
                        o_acc[qi][n] = __builtin_amdgcn_mfma_f32_16x16x32_bf16(pu.v, vf[n], o_acc[qi][n], 0, 0, 0);
                }
                __builtin_amdgcn_s_setprio(0);
            }
        }
        __builtin_amdgcn_s_barrier();
    }
#undef STAGE

    const int b = bh >> 4, h = bh & 15;
#pragma unroll
    for (int qi = 0; qi < 2; qi++) {
        const float linv = 1.f / ls[qi];
#pragma unroll
        for (int e = 0; e < 4; e++) {
            const float inv = __shfl(linv, (lane & 48) + (((lane >> 4) & 3) << 2) + e);
            const int t = qw0 + qi * 16 + g * 4 + e;
#pragma unroll
            for (int n = 0; n < 4; n++)
                o[((size_t)(b * TT + t)) * DD + h * HD + n * 16 + l15] = f2b(o_acc[qi][n][e] * inv);
        }
    }
}

// ---------------- launch ----------------

extern "C" void kernel_launch(void* const* d_in, const int* in_sizes, int n_in,
                              void* d_out, int out_size, void* d_ws, size_t ws_size,
                              hipStream_t stream)
{
    const float* x     = (const float*)d_in[0];
    const float* w_qkv = (const float*)d_in[1];
    const float* w_o   = (const float*)d_in[2];
    float* out = (float*)d_out;
    char* ws = (char*)d_ws;

    u16* xb    = (u16*)(ws);                 // 8192x1024        16 MB
    u16* wqkvT = (u16*)(ws + 16777216);      // 3072x1024         6 MB
    u16* woT   = (u16*)(ws + 23068672);      // 1024x1024         2 MB
    u16* wsq   = (u16*)(ws + 25165824);      // [B,H,T,64]       16 MB
    u16* wsk   = (u16*)(ws + 41943040);      // [B,H,T,64]       16 MB
    u16* wsvT  = (u16*)(ws + 58720256);      // [B,H,64,T]       16 MB
    u16* attno = (u16*)(ws + 75497472);      // [B*T, D]         16 MB

    f32_to_bf16_vec<<<8192, 256, 0, stream>>>(x, xb, 2097152);
    dim3 tb(32, 8);
    transpose_f32_bf16<<<dim3(96, 32), tb, 0, stream>>>(w_qkv, wqkvT, 1024, 3072);
    transpose_f32_bf16<<<dim3(32, 32), tb, 0, stream>>>(w_o,   woT,   1024, 1024);

    gemm_bt<0><<<dim3(24, 64), 256, 0, stream>>>(xb, wqkvT, 8192, 3072, 1024, wsq, wsk, wsvT, nullptr);
    attn_fwd<<<1024, 256, 0, stream>>>(wsq, wsk, wsvT, attno);
    gemm_bt<1><<<dim3(8, 64), 256, 0, stream>>>(attno, woT, 8192, 1024, 1024, nullptr, nullptr, nullptr, out);
}

// Round 5
// 168.177 us; speedup vs baseline: 2.1995x; 1.0347x over previous
//
#include <hip/hip_runtime.h>
#include <hip/hip_bf16.h>
#include <stdint.h>

#define HD 64
#define NH 16
#define TT 2048
#define DD 1024

typedef uint16_t u16;
typedef __bf16 bf16_t;
typedef bf16_t bf16x8 __attribute__((ext_vector_type(8)));
typedef float f32x4 __attribute__((ext_vector_type(4)));

__device__ __forceinline__ u16 f2b(float f) {
    union { float f; uint32_t u; } v; v.f = f;
    uint32_t u = v.u;
    u += 0x7fff + ((u >> 16) & 1);   // RNE
    return (u16)(u >> 16);
}

__device__ __forceinline__ u16 b16(float f) {
    union { __bf16 h; u16 u; } c; c.h = (__bf16)f; return c.u;  // HW cvt (RNE)
}

__device__ __forceinline__ void gload16(const void* g, void* l) {
    __builtin_amdgcn_global_load_lds(
        (__attribute__((address_space(1))) void*)g,
        (__attribute__((address_space(3))) void*)l, 16, 0, 0);
}

// ---------------- converts ----------------

__global__ void f32_to_bf16_vec(const float* __restrict__ in, u16* __restrict__ out, int n4) {
    int i = blockIdx.x * 256 + threadIdx.x;
    if (i >= n4) return;
    float4 v = ((const float4*)in)[i];
    ushort4 r;
    r.x = f2b(v.x); r.y = f2b(v.y); r.z = f2b(v.z); r.w = f2b(v.w);
    ((ushort4*)out)[i] = r;
}

// out[c][r] = bf16(in[r][c]); R,C multiples of 32; block (32,8)
__global__ void transpose_f32_bf16(const float* __restrict__ in, u16* __restrict__ out, int R, int C) {
    __shared__ float tile[32][33];
    const int tx = threadIdx.x, ty = threadIdx.y;
    const int c0 = blockIdx.x * 32, r0 = blockIdx.y * 32;
#pragma unroll
    for (int j = 0; j < 32; j += 8)
        tile[ty + j][tx] = in[(size_t)(r0 + ty + j) * C + c0 + tx];
    __syncthreads();
#pragma unroll
    for (int j = 0; j < 32; j += 8)
        out[(size_t)(c0 + ty + j) * R + r0 + tx] = f2b(tile[tx][ty + j]);
}

// ---------------- GEMM C = A[M,K] * Bt[N,K]^T, bf16 in, f32 acc ----------------
// LDS tiles [128][32] bf16, chunk (16B) XOR-swizzled by (row>>1)&3.
// TRIPLE-buffered (3-deep prefetch), counted vmcnt(8), raw s_barrier.
// Bijective XCD swizzle on the flattened workgroup id (nwg % 8 == 0 for both grids).
// MODE 0: scatter epilogue -> q (x0.125), k, vT   (N=3072)
// MODE 1: plain f32 store to of[M,N]

template<int MODE>
__global__ __launch_bounds__(256, 3)
void gemm_bt(const u16* __restrict__ A, const u16* __restrict__ Bt,
             int M, int N, int K,
             u16* __restrict__ oq, u16* __restrict__ ok, u16* __restrict__ ovT,
             float* __restrict__ of)
{
    __shared__ __align__(16) u16 As[3][128 * 32];
    __shared__ __align__(16) u16 Bs[3][128 * 32];
    const int tid = threadIdx.x;
    const int lane = tid & 63, l15 = lane & 15, g = lane >> 4;
    const int wv = tid >> 6, wr = wv >> 1, wc = wv & 1;

    // XCD-aware bijective swizzle: XCD k owns a contiguous chunk of x-major tiles
    const int gx = gridDim.x;
    const int nwg = gx * gridDim.y;
    const int wgid = blockIdx.y * gx + blockIdx.x;
    const int cpx = nwg >> 3;
    const int sid = (wgid & 7) * cpx + (wgid >> 3);
    const long row0 = (long)(sid / gx) * 128;
    const long col0 = (long)(sid % gx) * 128;

    const int cA = tid, cB = tid + 256;
    // staging source: chunk XOR-swizzled by (row>>1)&3 (row = c>>2, chunk = c&3)
    const u16* a0 = A + (row0 + (cA >> 2)) * K + (((cA & 3) ^ ((cA >> 3) & 3)) * 8);
    const u16* a1 = A + (row0 + (cB >> 2)) * K + (((cB & 3) ^ ((cB >> 3) & 3)) * 8);
    const u16* b0 = Bt + (col0 + (cA >> 2)) * K + (((cA & 3) ^ ((cA >> 3) & 3)) * 8);
    const u16* b1 = Bt + (col0 + (cB >> 2)) * K + (((cB & 3) ^ ((cB >> 3) & 3)) * 8);

    const f32x4 z4 = {0.f, 0.f, 0.f, 0.f};
    f32x4 acc[4][4];
#pragma unroll
    for (int i = 0; i < 4; i++)
#pragma unroll
        for (int n = 0; n < 4; n++) acc[i][n] = z4;

    const int swz = (l15 >> 1) & 3;   // read-side chunk XOR (row>>1)&3 == (l15>>1)&3

#define GSTAGE(buf, k0s)                          \
    do {                                          \
        gload16(a0 + (k0s), &As[buf][cA * 8]);    \
        gload16(a1 + (k0s), &As[buf][cB * 8]);    \
        gload16(b0 + (k0s), &Bs[buf][cA * 8]);    \
        gload16(b1 + (k0s), &Bs[buf][cB * 8]);    \
    } while (0)

    const int niter = K >> 5;          // 32 for K=1024
    GSTAGE(0, 0);
    GSTAGE(1, 32);
    int cur = 0, pre = 2;
    for (int it = 0; it < niter; ++it) {
        if (it + 2 < niter) {
            GSTAGE(pre, (it + 2) << 5);
            asm volatile("s_waitcnt vmcnt(8)" ::: "memory");   // tile it done; 2 tiles in flight
        } else if (it + 1 < niter) {
            asm volatile("s_waitcnt vmcnt(4)" ::: "memory");
        } else {
            asm volatile("s_waitcnt vmcnt(0)" ::: "memory");
        }
        __builtin_amdgcn_s_barrier();
        bf16x8 af[4], bfr[4];
#pragma unroll
        for (int i = 0; i < 4; i++)
            af[i]  = *(const bf16x8*)&As[cur][(wr * 64 + i * 16 + l15) * 32 + ((g ^ swz) << 3)];
#pragma unroll
        for (int n = 0; n < 4; n++)
            bfr[n] = *(const bf16x8*)&Bs[cur][(wc * 64 + n * 16 + l15) * 32 + ((g ^ swz) << 3)];
        __builtin_amdgcn_s_setprio(1);
#pragma unroll
        for (int i = 0; i < 4; i++)
#pragma unroll
            for (int n = 0; n < 4; n++)
                acc[i][n] = __builtin_amdgcn_mfma_f32_16x16x32_bf16(af[i], bfr[n], acc[i][n], 0, 0, 0);
        __builtin_amdgcn_s_setprio(0);
        __builtin_amdgcn_s_barrier();
        cur = (cur == 2) ? 0 : cur + 1;
        pre = (pre == 2) ? 0 : pre + 1;
    }
#undef GSTAGE

    if (MODE == 0) {
        const int which = (int)(col0 >> 10);
        const long b = row0 >> 11;
#pragma unroll
        for (int i = 0; i < 4; i++) {
            const long r = row0 + wr * 64 + i * 16 + g * 4;
            const long t = r & (TT - 1);
#pragma unroll
            for (int n = 0; n < 4; n++) {
                const long c = col0 + wc * 64 + n * 16 + l15;
                const int h  = (int)((c >> 6) & 15);
                const int hd = (int)(c & 63);
                if (which == 0) {
#pragma unroll
                    for (int e = 0; e < 4; e++)
                        oq[((b * NH + h) * TT + t + e) * HD + hd] = f2b(acc[i][n][e] * 0.125f);
                } else if (which == 1) {
#pragma unroll
                    for (int e = 0; e < 4; e++)
                        ok[((b * NH + h) * TT + t + e) * HD + hd] = f2b(acc[i][n][e]);
                } else {
                    ushort4 pk;
                    pk.x = f2b(acc[i][n][0]); pk.y = f2b(acc[i][n][1]);
                    pk.z = f2b(acc[i][n][2]); pk.w = f2b(acc[i][n][3]);
                    *(ushort4*)&ovT[((b * NH + h) * HD + hd) * TT + t] = pk;
                }
            }
        }
    } else {
#pragma unroll
        for (int i = 0; i < 4; i++) {
            const long r = row0 + wr * 64 + i * 16 + g * 4;
#pragma unroll
            for (int n = 0; n < 4; n++) {
                const long c = col0 + wc * 64 + n * 16 + l15;
#pragma unroll
                for (int e = 0; e < 4; e++)
                    of[(r + e) * (long)N + c] = acc[i][n][e];
            }
        }
    }
}

// ---------------- flash attention ----------------
// 1D grid: blockIdx.x -> (qt heavy-first, bh). 256 threads (4 waves x 32 q).
// KV tiles of 64 keys, double-buffered, counted vmcnt, raw s_barrier.
// K/V LDS XOR-swizzled (chunk ^ row&7, via pre-swizzled global src).
// QK^T computed SWAPPED: s = mfma(K,Q) -> q = lane&15, key = g*4+e (in-lane row).
// P repacked through per-wave LDS as 8B granules, granule ^ (l15&15) swizzle.

__global__ __launch_bounds__(256, 3)
void attn_fwd(const u16* __restrict__ gq, const u16* __restrict__ gk,
              const u16* __restrict__ gvT, u16* __restrict__ o)
{
    __shared__ __align__(16) u16 Klds[2][64 * 64];   // [key][hd] swizzled
    __shared__ __align__(16) u16 Vlds[2][64 * 64];   // [hd][key] swizzled
    __shared__ __align__(16) u16 Plds[4][32 * 64];   // per-wave [q][16 x 8B granules]

    const int tid = threadIdx.x;
    const int wv = tid >> 6, lane = tid & 63, l15 = lane & 15, g = lane >> 4;
    const int bh = blockIdx.x & 63;
    const int qt = 15 - (blockIdx.x >> 6);       // heavy tiles dispatch first
    const int q0 = qt * 128;
    const int qw0 = q0 + wv * 32;

    const u16* qbase = gq + (size_t)bh * TT * HD;
    const u16* kbase = gk + (size_t)bh * TT * HD;
    const u16* vbase = gvT + (size_t)bh * HD * TT;

    const float NEG_INF = -__builtin_inff();
    const f32x4 z4 = {0.f, 0.f, 0.f, 0.f};

    bf16x8 qf[2][2];
#pragma unroll
    for (int qi = 0; qi < 2; qi++)
#pragma unroll
        for (int hs = 0; hs < 2; hs++)
            qf[qi][hs] = *(const bf16x8*)(qbase + (size_t)(qw0 + qi * 16 + l15) * HD + hs * 32 + g * 8);

    f32x4 o_acc[2][4];
    float m[2], ls[2];
#pragma unroll
    for (int qi = 0; qi < 2; qi++) {
#pragma unroll
        for (int n = 0; n < 4; n++) o_acc[qi][n] = z4;
        m[qi] = NEG_INF; ls[qi] = 0.f;
    }

    // staging lane roles (same for K and V): per call each thread loads 2 chunks of each
    const int r0_ = tid >> 3, c0_ = tid & 7;            // chunk (r0_, c0_)
    const int r1_ = (tid + 256) >> 3, c1_ = (tid + 256) & 7;

#define STAGE(buf, k0s)                                                                    \
    do {                                                                                   \
        gload16(kbase + (size_t)((k0s) + r0_) * HD + ((c0_ ^ (r0_ & 7)) * 8), &Klds[buf][tid * 8]);          \
        gload16(kbase + (size_t)((k0s) + r1_) * HD + ((c1_ ^ (r1_ & 7)) * 8), &Klds[buf][(tid + 256) * 8]);  \
        gload16(vbase + (size_t)r0_ * TT + (k0s) + ((c0_ ^ (r0_ & 7)) * 8), &Vlds[buf][tid * 8]);            \
        gload16(vbase + (size_t)r1_ * TT + (k0s) + ((c1_ ^ (r1_ & 7)) * 8), &Vlds[buf][(tid + 256) * 8]);    \
    } while (0)

    const int nkt = q0 / 64 + 2;
    STAGE(0, 0);
    for (int kt = 0; kt < nkt; ++kt) {
        const int k0 = kt * 64;
        const int cur = kt & 1;
        if (kt + 1 < nkt) {
            STAGE(cur ^ 1, k0 + 64);
            asm volatile("s_waitcnt vmcnt(4)" ::: "memory");  // tile kt's 4 loads done
        } else {
            asm volatile("s_waitcnt vmcnt(0)" ::: "memory");
        }
        __builtin_amdgcn_s_barrier();
        if (k0 <= qw0 + 31) {
            const int sw = l15 & 7;   // row&7 for K rows (kb*16+l15) and V rows (n*16+l15)
            // swapped QK^T: s2[qi][kb]: q = qi*16 + l15, key = k0 + kb*16 + g*4 + e
            f32x4 s2[2][4];
            __builtin_amdgcn_s_setprio(1);
#pragma unroll
            for (int kb = 0; kb < 4; kb++) {
                bf16x8 kf0 = *(const bf16x8*)&Klds[cur][(kb * 16 + l15) * 64 + ((g ^ sw) * 8)];
                bf16x8 kf1 = *(const bf16x8*)&Klds[cur][(kb * 16 + l15) * 64 + (((4 + g) ^ sw) * 8)];
#pragma unroll
                for (int qi = 0; qi < 2; qi++) {
                    f32x4 t0 = __builtin_amdgcn_mfma_f32_16x16x32_bf16(kf0, qf[qi][0], z4, 0, 0, 0);
                    s2[qi][kb] = __builtin_amdgcn_mfma_f32_16x16x32_bf16(kf1, qf[qi][1], t0, 0, 0, 0);
                }
            }
            __builtin_amdgcn_s_setprio(0);
            if (k0 + 63 > qw0) {
#pragma unroll
                for (int qi = 0; qi < 2; qi++)
#pragma unroll
                    for (int kb = 0; kb < 4; kb++)
#pragma unroll
                        for (int e = 0; e < 4; e++) {
                            const int kk = k0 + kb * 16 + g * 4 + e;
                            const int qq = qw0 + qi * 16 + l15;
                            if (kk > qq) s2[qi][kb][e] = NEG_INF;
                        }
            }
            // in-register online softmax (q = l15 per lane)
#pragma unroll
            for (int qi = 0; qi < 2; qi++) {
                f32x4 mx = s2[qi][0];
#pragma unroll
                for (int kb = 1; kb < 4; kb++)
#pragma unroll
                    for (int e = 0; e < 4; e++) mx[e] = fmaxf(mx[e], s2[qi][kb][e]);
                float pmax = fmaxf(fmaxf(mx[0], mx[1]), fmaxf(mx[2], mx[3]));
                pmax = fmaxf(pmax, __shfl_xor(pmax, 16));
                pmax = fmaxf(pmax, __shfl_xor(pmax, 32));
                float mn = m[qi];
                const int resc = !__all(pmax <= mn + 8.f);   // T13 defer-max
                if (resc) {
                    const float mold = mn;
                    mn = fmaxf(mold, pmax);
                    m[qi] = mn;
                    const float sc = __expf(mold - mn);
                    ls[qi] *= sc;
#pragma unroll
                    for (int e = 0; e < 4; e++) {
                        const float sce = __shfl(sc, (lane & 48) + (((lane >> 4) & 3) << 2) + e);
#pragma unroll
                        for (int n = 0; n < 4; n++) o_acc[qi][n][e] *= sce;
                    }
                }
                const int prow = qi * 16 + l15;
                u16* pb = &Plds[wv][prow * 64];
                float rsum = 0.f;
#pragma unroll
                for (int kb = 0; kb < 4; kb++) {
                    const float p0 = __expf(s2[qi][kb][0] - mn);
                    const float p1 = __expf(s2[qi][kb][1] - mn);
                    const float p2 = __expf(s2[qi][kb][2] - mn);
                    const float p3 = __expf(s2[qi][kb][3] - mn);
                    rsum += (p0 + p1) + (p2 + p3);
                    ushort4 pk;
                    pk.x = b16(p0); pk.y = b16(p1); pk.z = b16(p2); pk.w = b16(p3);
                    *(ushort4*)&pb[(((kb << 2) + g) ^ l15) * 4] = pk;
                }
                rsum += __shfl_xor(rsum, 16);
                rsum += __shfl_xor(rsum, 32);
                ls[qi] += rsum;
            }
            // PV: A = P (row q=l15, keys g*8+j), B = V^T
#pragma unroll
            for (int ks = 0; ks < 2; ks++) {
                bf16x8 vf[4];
#pragma unroll
                for (int n = 0; n < 4; n++)
                    vf[n] = *(const bf16x8*)&Vlds[cur][(n * 16 + l15) * 64 + (((ks * 4 + g) ^ sw) * 8)];
                __builtin_amdgcn_s_setprio(1);
#pragma unroll
                for (int qi = 0; qi < 2; qi++) {
                    const u16* pb = &Plds[wv][(qi * 16 + l15) * 64];
                    const int G0 = ((ks << 3) + (g << 1)) ^ l15;
                    const int G1 = ((ks << 3) + (g << 1) + 1) ^ l15;
                    const uint2 ra = *(const uint2*)&pb[G0 * 4];
                    const uint2 rb = *(const uint2*)&pb[G1 * 4];
                    union { uint32_t w[4]; bf16x8 v; } pu;
                    pu.w[0] = ra.x; pu.w[1] = ra.y; pu.w[2] = rb.x; pu.w[3] = rb.y;
#pragma unroll
                    for (int n = 0; n < 4; n++)
                        o_acc[qi][n] = __builtin_amdgcn_mfma_f32_16x16x32_bf16(pu.v, vf[n], o_acc[qi][n], 0, 0, 0);
                }
                __builtin_amdgcn_s_setprio(0);
            }
        }
        __builtin_amdgcn_s_barrier();
    }
#undef STAGE

    const int b = bh >> 4, h = bh & 15;
#pragma unroll
    for (int qi = 0; qi < 2; qi++) {
        const float linv = 1.f / ls[qi];
#pragma unroll
        for (int e = 0; e < 4; e++) {
            const float inv = __shfl(linv, (lane & 48) + (((lane >> 4) & 3) << 2) + e);
            const int t = qw0 + qi * 16 + g * 4 + e;
#pragma unroll
            for (int n = 0; n < 4; n++)
                o[((size_t)(b * TT + t)) * DD + h * HD + n * 16 + l15] = f2b(o_acc[qi][n][e] * inv);
        }
    }
}

// ---------------- launch ----------------

extern "C" void kernel_launch(void* const* d_in, const int* in_sizes, int n_in,
                              void* d_out, int out_size, void* d_ws, size_t ws_size,
                              hipStream_t stream)
{
    const float* x     = (const float*)d_in[0];
    const float* w_qkv = (const float*)d_in[1];
    const float* w_o   = (const float*)d_in[2];
    float* out = (float*)d_out;
    char* ws = (char*)d_ws;

    u16* xb    = (u16*)(ws);                 // 8192x1024        16 MB
    u16* wqkvT = (u16*)(ws + 16777216);      // 3072x1024         6 MB
    u16* woT   = (u16*)(ws + 23068672);      // 1024x1024         2 MB
    u16* wsq   = (u16*)(ws + 25165824);      // [B,H,T,64]       16 MB
    u16* wsk   = (u16*)(ws + 41943040);      // [B,H,T,64]       16 MB
    u16* wsvT  = (u16*)(ws + 58720256);      // [B,H,64,T]       16 MB
    u16* attno = (u16*)(ws + 75497472);      // [B*T, D]         16 MB

    f32_to_bf16_vec<<<8192, 256, 0, stream>>>(x, xb, 2097152);
    dim3 tb(32, 8);
    transpose_f32_bf16<<<dim3(96, 32), tb, 0, stream>>>(w_qkv, wqkvT, 1024, 3072);
    transpose_f32_bf16<<<dim3(32, 32), tb, 0, stream>>>(w_o,   woT,   1024, 1024);

    gemm_bt<0><<<dim3(24, 64), 256, 0, stream>>>(xb, wqkvT, 8192, 3072, 1024, wsq, wsk, wsvT, nullptr);
    attn_fwd<<<1024, 256, 0, stream>>>(wsq, wsk, wsvT, attno);
    gemm_bt<1><<<dim3(8, 64), 256, 0, stream>>>(attno, woT, 8192, 1024, 1024, nullptr, nullptr, nullptr, out);
}